// Round 8
// baseline (7209.627 us; speedup 1.0000x reference)
//
#include <hip/hip_runtime.h>
#include <cfloat>
#include <math.h>

#define N 512
typedef unsigned long long u64_t;

__device__ __forceinline__ u64_t map_f64(double x) {
    u64_t b = (u64_t)__double_as_longlong(x);
    return b ^ ((b >> 63) ? 0xFFFFFFFFFFFFFFFFull : 0x8000000000000000ull);
}
__device__ __forceinline__ double unmap_f64(u64_t b) {
    b ^= ((b >> 63) ? 0x8000000000000000ull : 0xFFFFFFFFFFFFFFFFull);
    return __longlong_as_double((long long)b);
}

// wave64 u64 min-reduce via DPP (VALU pipe). Valid result in lane 63.
__device__ __forceinline__ u64_t wave_min_key(u64_t key) {
    unsigned hi = (unsigned)(key >> 32), lo = (unsigned)key;
#define MIN_STAGE(CTRL)                                                        \
    {                                                                          \
        unsigned oh = (unsigned)__builtin_amdgcn_update_dpp((int)hi, (int)hi,  \
                                                            CTRL, 0xF, 0xF, false); \
        unsigned ol = (unsigned)__builtin_amdgcn_update_dpp((int)lo, (int)lo,  \
                                                            CTRL, 0xF, 0xF, false); \
        const u64_t o = ((u64_t)oh << 32) | ol;                                \
        const u64_t c = ((u64_t)hi << 32) | lo;                                \
        if (o < c) { hi = oh; lo = ol; }                                       \
    }
    MIN_STAGE(0x111) MIN_STAGE(0x112) MIN_STAGE(0x114) MIN_STAGE(0x118)
    MIN_STAGE(0x142) MIN_STAGE(0x143)
#undef MIN_STAGE
    return ((u64_t)hi << 32) | lo;
}

// rowdat[i]: .x = packed (f32 b | f32 d), .y = u[i]. One b128 read per use.
__device__ __forceinline__ void rd_decode(const double2 rd, double& b, double& d,
                                          double& u) {
    const u64_t bits = (u64_t)__double_as_longlong(rd.x);
    b = (double)__uint_as_float((unsigned)bits);        // f32-exact widen
    d = (double)__uint_as_float((unsigned)(bits >> 32));
    u = rd.y;
}

// 512 threads / 8 waves, thread t = column t+1. Exact JV (R5 core) +
// free-column v-tightening: v[free j] kept at min_i(c(i,j)-u[i]) via an
// incremental changed-row list => short Dijkstra trees.
// key = [45b value | 9b col-1 | 10b p[col]] (truncation: absmax 0 in R3-R7).
__global__ __launch_bounds__(512, 1) void tofu_solver(
    const float* __restrict__ dgm, const float* __restrict__ dgm_x,
    float* __restrict__ out)
{
#pragma clang fp contract(off)
    __shared__ double2 rowdat[N + 1];
    __shared__ int     p_lds[N + 1];
    __shared__ int     way_lds[N + 1];
    __shared__ int     claim[N + 1];
    __shared__ int     flist[4 * N + 32];
    __shared__ int     chg[N + 8];      // rows whose u changed last Dijkstra
    __shared__ u64_t   dslot[3];
    __shared__ u64_t   aslot[2], bslot[2];
    __shared__ double  v1x;
    __shared__ double  red8[8];
    __shared__ int     nfree_s, nchg;

    const int tid  = threadIdx.x;       // 0..511
    const int col  = tid + 1;           // 1..512
    const int lane = tid & 63;
    const int wid  = tid >> 6;
    const float2* dgm2  = (const float2*)dgm;
    const float2* dgmx2 = (const float2*)dgm_x;

    // ---- stage ----
    {
        const float2 p2 = dgm2[tid];
        double2 rd;
        rd.x = __longlong_as_double((long long)(
                   ((u64_t)__float_as_uint(p2.y) << 32) | __float_as_uint(p2.x)));
        rd.y = 0.0;
        rowdat[col] = rd;
    }
    const float2 q2 = dgmx2[tid];
    const double xb = (double)q2.x, xd = (double)q2.y;
    p_lds[col] = 0; way_lds[col] = 0; claim[col] = 0x7fffffff;
    if (tid == 0) {
        rowdat[0] = make_double2(0.0, 0.0);
        p_lds[0] = 0; way_lds[0] = 0; claim[0] = 0x7fffffff;
        dslot[0] = dslot[1] = dslot[2] = ~0ull;
        aslot[0] = aslot[1] = ~0ull; bslot[0] = bslot[1] = ~0ull;
        nchg = 0;
    }
    __syncthreads();

    // ---- column reduction: v[j]=min_i c(i,j) (sq-dist argmin; sqrt monotone) ----
    double v_j; int amin;
    {
        double vsq = DBL_MAX; amin = 1;
        for (int i = 1; i <= N; ++i) {
            const double2 rd = rowdat[i];             // broadcast b128
            double rb, rdd, ru; rd_decode(rd, rb, rdd, ru);
            const double db = rb - xb, dd = rdd - xd;
            const double sq = db * db + dd * dd;
            if (sq < vsq) { vsq = sq; amin = i; }
        }
        v_j = sqrt(vsq);
    }

    // ---- greedy: row r -> smallest col whose argmin is r (tight, u=0) ----
    int myp = 0;
    atomicMin(&claim[amin], col);
    __syncthreads();
    if (claim[amin] == col) { p_lds[col] = amin; myp = amin; }
    __syncthreads();

    // ---- freelist of unmatched rows ----
    claim[col] = 0;
    __syncthreads();
    { const int r = p_lds[col]; if (r) claim[r] = 1; }
    __syncthreads();
    if (tid == 0) {
        int nf = 0;
        for (int r = 1; r <= N; ++r) if (!claim[r]) flist[nf++] = r;
        nfree_s = nf;
    }
    __syncthreads();

    // ---- sequential ARR (R5 logic, exactness-preserving, capped) ----
    {
        int head = 0, tail = nfree_s, q = 0;
        const int cap = 3 * tail + 16;
        for (int step = 0; step < cap && head < tail; ++step) {
            const int i = flist[head++];              // uniform broadcast
            const double2 rd = rowdat[i];
            double rb, rdd, ru; rd_decode(rd, rb, rdd, ru);
            const double db = rb - xb, dd = rdd - xd;
            const double val = sqrt(db * db + dd * dd) - v_j;
            const u64_t key = (map_f64(val) & ~0x7FFFFull)
                            | ((u64_t)(col - 1) << 10) | (u64_t)myp;
            u64_t kr = wave_min_key(key);
            if (lane == 63) atomicMin(&aslot[q], kr);
            __syncthreads();
            const u64_t k1 = aslot[q];
            const int j1    = (int)((k1 >> 10) & 511) + 1;
            const int k_old = (int)(k1 & 1023);
            if (col == j1) v1x = val;                 // exact v1 handoff
            kr = wave_min_key((col == j1) ? ~0ull : key);
            if (lane == 63) atomicMin(&bslot[q], kr);
            __syncthreads();
            const double m2t = unmap_f64(bslot[q] & ~0x7FFFFull);
            const double ui  = fmax(m2t, v1x);        // feasible AND tight on j1
            if (col == j1) { v_j -= (ui - val); myp = i; }
            if (tid == 0) {
                rowdat[i].y = ui;
                p_lds[j1] = i;
                if (k_old) flist[tail] = k_old;
                aslot[q ^ 1] = ~0ull; bslot[q ^ 1] = ~0ull;
            }
            if (k_old) ++tail;                        // uniform
            q ^= 1;
            __syncthreads();
        }
    }

    // ---- rebuild freelist from p ----
    claim[col] = 0;
    __syncthreads();
    { const int r = p_lds[col]; if (r) claim[r] = 1; }
    __syncthreads();
    if (tid == 0) {
        int nf = 0;
        for (int r = 1; r <= N; ++r) if (!claim[r]) flist[nf++] = r;
        nfree_s = nf;
    }
    __syncthreads();
    const int nfree = nfree_s;

    // ---- full tighten: m = min_i (c(i,col) - u[i]); raise v of free cols ----
    double mtight = DBL_MAX;
    for (int i = 1; i <= N; ++i) {
        const double2 rd = rowdat[i];                 // broadcast b128
        double rb, rdd, ru; rd_decode(rd, rb, rdd, ru);
        const double db = rb - xb, dd = rdd - xd;
        mtight = fmin(mtight, sqrt(db * db + dd * dd) - ru);
    }
    if (p_lds[col] == 0) v_j = fmax(v_j, mtight);     // feasible: v <= m always

    // ---- exact Dijkstra phase ----
    for (int kk = 0; kk < nfree; ++kk) {
        const int iroot = flist[kk];
        // incremental tighten: fold rows whose u rose last Dijkstra (exact f64)
        const int nc = nchg;                          // visible via epilogue barrier
        for (int k = 0; k < nc; ++k) {
            const int r = chg[k];                     // broadcast
            const double2 rd = rowdat[r];
            double rb, rdd, ru; rd_decode(rd, rb, rdd, ru);
            const double db = rb - xb, dd = rdd - xd;
            mtight = fmin(mtight, sqrt(db * db + dd * dd) - ru);
        }
        if (p_lds[col] == 0) v_j = fmax(v_j, mtight); // raise only free columns
        __syncthreads();                              // consume before reset
        if (tid == 0) { nchg = 0; p_lds[0] = iroot; } // p[0]: augment terminator
        const int pcol = p_lds[col];                  // static this Dijkstra
        double minv = DBL_MAX, du = 0.0, du0 = 0.0;
        bool used = false;
        int juse = 0, i0 = iroot, par = 0;

        while (true) {
            if (col == juse) used = true;             // mark prev winner
            const double2 rd = rowdat[i0];            // ONE b128: point + u
            double rb, rdd, u0; rd_decode(rd, rb, rdd, u0);
            u64_t key = ~0ull;
            if (!used) {
                const double db = rb - xb, dd = rdd - xd;
                const double c = sqrt(db * db + dd * dd);
                const double cur = (c - u0) - v_j;
                if (cur < minv) { minv = cur; way_lds[col] = juse; }
                key = (map_f64(minv) & ~0x7FFFFull)
                    | ((u64_t)(col - 1) << 10) | (u64_t)pcol;
            }
            key = wave_min_key(key);
            if (lane == 63) atomicMin(&dslot[par], key);
            __syncthreads();
            const u64_t k = dslot[par];
            if (tid == 0) dslot[(par + 2) % 3] = ~0ull;   // read 2 barriers ago
            const double delta = unmap_f64(k & ~0x7FFFFull);
            if (used) { v_j -= delta; du += delta; }
            else        minv -= delta;
            if (tid == 0) du0 += delta;
            juse = (int)((k >> 10) & 511) + 1;
            i0   = (int)(k & 1023);                   // p payload; 0 => free col
            if (i0 == 0) break;
            par = (par + 1) % 3;
        }

        // epilogue: flush duals, record changed rows, augment, clean slot
        if (used) {
            rowdat[pcol].y += du;                     // distinct rows: race-free
            const int ix = atomicAdd(&nchg, 1);
            chg[ix] = pcol;
        }
        if (tid == 0) {
            rowdat[iroot].y += du0;
            const int ix = atomicAdd(&nchg, 1);
            chg[ix] = iroot;
            dslot[par] = ~0ull;
            int j = juse;
            while (j) { const int jn = way_lds[j]; p_lds[j] = p_lds[jn]; j = jn; }
        }
        __syncthreads();
    }

    // ---- loss = 0.5 * sum_j ||dgm[p[j]-1] - dgm_x[j-1]||^2 (f32 diffs like ref) ----
    const int r = p_lds[col] - 1;
    const float2 a = dgm2[r];
    const float2 b = dgmx2[tid];
    const float fb = a.x - b.x;
    const float fd = a.y - b.y;
    double acc = (double)fb * (double)fb + (double)fd * (double)fd;
    #pragma unroll
    for (int m = 32; m >= 1; m >>= 1) acc += __shfl_xor(acc, m, 64);
    if (lane == 0) red8[wid] = acc;
    __syncthreads();
    if (tid == 0) {
        double s = 0.0;
        #pragma unroll
        for (int w = 0; w < 8; ++w) s += red8[w];
        out[0] = (float)(0.5 * s);
    }
}

extern "C" void kernel_launch(void* const* d_in, const int* in_sizes, int n_in,
                              void* d_out, int out_size, void* d_ws, size_t ws_size,
                              hipStream_t stream) {
    const float* dgm   = (const float*)d_in[0];
    const float* dgm_x = (const float*)d_in[1];
    float* out = (float*)d_out;
    tofu_solver<<<1, 512, 0, stream>>>(dgm, dgm_x, out);
}

// Round 9
// 5755.410 us; speedup vs baseline: 1.2527x; 1.2527x over previous
//
#include <hip/hip_runtime.h>
#include <cfloat>
#include <math.h>

#define N 512
typedef unsigned long long u64_t;

__device__ __forceinline__ u64_t map_f64(double x) {
    u64_t b = (u64_t)__double_as_longlong(x);
    return b ^ ((b >> 63) ? 0xFFFFFFFFFFFFFFFFull : 0x8000000000000000ull);
}
__device__ __forceinline__ double unmap_f64(u64_t b) {
    b ^= ((b >> 63) ? 0x8000000000000000ull : 0xFFFFFFFFFFFFFFFFull);
    return __longlong_as_double((long long)b);
}

// wave64 u64 min-reduce via DPP (VALU pipe). Valid result in lane 63.
__device__ __forceinline__ u64_t wave_min_key(u64_t key) {
    unsigned hi = (unsigned)(key >> 32), lo = (unsigned)key;
#define MIN_STAGE(CTRL)                                                        \
    {                                                                          \
        unsigned oh = (unsigned)__builtin_amdgcn_update_dpp((int)hi, (int)hi,  \
                                                            CTRL, 0xF, 0xF, false); \
        unsigned ol = (unsigned)__builtin_amdgcn_update_dpp((int)lo, (int)lo,  \
                                                            CTRL, 0xF, 0xF, false); \
        const u64_t o = ((u64_t)oh << 32) | ol;                                \
        const u64_t c = ((u64_t)hi << 32) | lo;                                \
        if (o < c) { hi = oh; lo = ol; }                                       \
    }
    MIN_STAGE(0x111) MIN_STAGE(0x112) MIN_STAGE(0x114) MIN_STAGE(0x118)
    MIN_STAGE(0x142) MIN_STAGE(0x143)
#undef MIN_STAGE
    return ((u64_t)hi << 32) | lo;
}

// 512 threads / 8 waves, thread t owns column t+1. Exact JV:
// column reduction + greedy tight match + LAPJV ARR warm start, then
// Dijkstra with DPP wave-reduce + 8-way ds_min_u64 combine.
// key = [45b value | 9b col-1 | 10b p[col]] (truncation precedent: R3-R8 absmax 0).
// R9 = exact revert to the measured R5 optimum (5.75 ms). R4/R6/R7/R8
// deviations (1-wave, TG warm start, 4-wave, v-tightening) all regressed.
__global__ __launch_bounds__(512, 1) void tofu_solver(
    const float* __restrict__ dgm, const float* __restrict__ dgm_x,
    float* __restrict__ out)
{
#pragma clang fp contract(off)
    __shared__ double2 pt[N];
    __shared__ double  u_lds[N + 1];
    __shared__ int     p_lds[N + 1];
    __shared__ int     way_lds[N + 1];
    __shared__ int     claim[N + 1];
    __shared__ int     flist[4 * N + 32];
    __shared__ u64_t   dslot[3];        // Dijkstra combine slots (mod-3 rotation)
    __shared__ u64_t   aslot[2], bslot[2];  // ARR slots (parity)
    __shared__ double  v1x;
    __shared__ double  red8[8];
    __shared__ int     nfree_s;

    const int tid  = threadIdx.x;       // 0..511
    const int col  = tid + 1;           // 1..512
    const int lane = tid & 63;
    const int wid  = tid >> 6;
    const float2* dgm2  = (const float2*)dgm;
    const float2* dgmx2 = (const float2*)dgm_x;

    // ---- stage points; own column's target point in registers ----
    {
        const float2 p2 = dgm2[tid];
        pt[tid] = make_double2((double)p2.x, (double)p2.y);
    }
    const float2 q2 = dgmx2[tid];
    const double xb = (double)q2.x, xd = (double)q2.y;
    u_lds[col] = 0.0; p_lds[col] = 0; way_lds[col] = 0; claim[col] = 0x7fffffff;
    if (tid == 0) {
        u_lds[0] = 0.0; p_lds[0] = 0; way_lds[0] = 0; claim[0] = 0x7fffffff;
        dslot[0] = dslot[1] = dslot[2] = ~0ull;
        aslot[0] = aslot[1] = ~0ull; bslot[0] = bslot[1] = ~0ull;
    }
    __syncthreads();

    // ---- column reduction: argmin over squared dist (sqrt monotone => same v) ----
    double v_j; int amin;
    {
        double vsq = DBL_MAX; amin = 1;
        for (int i = 0; i < N; ++i) {
            const double2 rp = pt[i];                 // broadcast b128
            const double db = rp.x - xb, dd = rp.y - xd;
            const double sq = db * db + dd * dd;
            if (sq < vsq) { vsq = sq; amin = i + 1; }
        }
        v_j = sqrt(vsq);                              // exact: sqrt(min) == min(sqrt)
    }

    // ---- greedy tight matching: row r -> smallest col whose argmin is r ----
    atomicMin(&claim[amin], col);
    __syncthreads();
    if (claim[amin] == col) p_lds[col] = amin;        // tight: c=v[col], u=0
    __syncthreads();
    // freelist of unmatched rows
    claim[col] = 0;
    __syncthreads();
    { const int r = p_lds[col]; if (r) claim[r] = 1; }
    __syncthreads();
    if (tid == 0) {
        int nf = 0;
        for (int r = 1; r <= N; ++r) if (!claim[r]) flist[nf++] = r;
        nfree_s = nf;
    }
    __syncthreads();

    // ---- LAPJV augmenting row reduction (exactness-preserving, capped) ----
    {
        int head = 0, tail = nfree_s, q = 0;
        const int cap = 3 * tail + 16;
        int myp = p_lds[col];                          // register copy of p[col]
        for (int step = 0; step < cap && head < tail; ++step) {
            const int i = flist[head++];               // uniform broadcast
            const double2 rp = pt[i - 1];
            const double db = rp.x - xb, dd = rp.y - xd;
            const double val = sqrt(db * db + dd * dd) - v_j;   // exact f64
            const u64_t key = (map_f64(val) & ~0x7FFFFull)
                            | ((u64_t)(col - 1) << 10) | (u64_t)myp;
            u64_t kr = wave_min_key(key);
            if (lane == 63) atomicMin(&aslot[q], kr);
            __syncthreads();                           // barrier 1
            const u64_t k1 = aslot[q];
            const int j1    = (int)((k1 >> 10) & 511) + 1;
            const int k_old = (int)(k1 & 1023);
            if (col == j1) v1x = val;                  // exact v1 handoff
            kr = wave_min_key((col == j1) ? ~0ull : key);
            if (lane == 63) atomicMin(&bslot[q], kr);
            __syncthreads();                           // barrier 2
            const double m2t = unmap_f64(bslot[q] & ~0x7FFFFull);  // <= true 2nd-min
            const double v1e = v1x;
            const double ui  = fmax(m2t, v1e);         // feasible AND tight on j1
            if (col == j1) { v_j -= (ui - val); myp = i; }
            if (tid == 0) {
                u_lds[i] = ui;
                p_lds[j1] = i;
                if (k_old) flist[tail] = k_old;
                aslot[q ^ 1] = ~0ull; bslot[q ^ 1] = ~0ull;  // 2 barriers since read
            }
            if (k_old) ++tail;                         // uniform
            q ^= 1;
            __syncthreads();                           // barrier 3
        }
    }

    // ---- rebuild freelist from p ----
    claim[col] = 0;
    __syncthreads();
    { const int r = p_lds[col]; if (r) claim[r] = 1; }
    __syncthreads();
    if (tid == 0) {
        int nf = 0;
        for (int r = 1; r <= N; ++r) if (!claim[r]) flist[nf++] = r;
        nfree_s = nf;
    }
    __syncthreads();
    const int nfree = nfree_s;

    // ---- exact Dijkstra phase ----
    for (int kk = 0; kk < nfree; ++kk) {
        const int iroot = flist[kk];                   // ordered by prev end barrier
        const int pcol  = p_lds[col];                  // static during this Dijkstra
        if (tid == 0) p_lds[0] = iroot;                // only tid0 reads p[0] (augment)
        double minv = DBL_MAX, du = 0.0, du0 = 0.0;
        bool used = false;
        int juse = 0, i0 = iroot, par = 0;

        while (true) {
            // ---- A-phase ----
            if (col == juse) used = true;              // mark prev winner
            const double2 rp = pt[i0 - 1];             // broadcast b128
            const double u0 = u_lds[i0];               // untouched this Dijkstra
            u64_t key = ~0ull;
            if (!used) {
                const double db = rp.x - xb, dd = rp.y - xd;
                const double c = sqrt(db * db + dd * dd);
                const double cur = (c - u0) - v_j;
                if (cur < minv) { minv = cur; way_lds[col] = juse; }
                key = (map_f64(minv) & ~0x7FFFFull)
                    | ((u64_t)(col - 1) << 10) | (u64_t)pcol;
            }
            key = wave_min_key(key);
            if (lane == 63) atomicMin(&dslot[par], key);
            __syncthreads();
            // ---- B-phase ----
            const u64_t k = dslot[par];
            if (tid == 0) dslot[(par + 2) % 3] = ~0ull;  // last read 2 barriers ago
            const double delta = unmap_f64(k & ~0x7FFFFull);  // <= every free minv
            if (used) { v_j -= delta; du += delta; }
            else        minv -= delta;
            if (tid == 0) du0 += delta;
            juse = (int)((k >> 10) & 511) + 1;
            i0   = (int)(k & 1023);                    // p payload; 0 => free col
            if (i0 == 0) break;
            par = (par + 1) % 3;
        }

        // epilogue: flush duals (distinct rows => race-free), augment, clean slot
        if (used) u_lds[pcol] += du;
        if (tid == 0) {
            u_lds[iroot] += du0;
            dslot[par] = ~0ull;                        // the slot just consumed
            int j = juse;
            while (j) { const int jn = way_lds[j]; p_lds[j] = p_lds[jn]; j = jn; }
        }
        __syncthreads();
    }

    // ---- loss = 0.5 * sum_j ||dgm[p[j]-1] - dgm_x[j-1]||^2 (f32 diffs like ref) ----
    const int r = p_lds[col] - 1;
    const float2 a = dgm2[r];
    const float2 b = dgmx2[tid];
    const float fb = a.x - b.x;
    const float fd = a.y - b.y;
    double acc = (double)fb * (double)fb + (double)fd * (double)fd;
    #pragma unroll
    for (int m = 32; m >= 1; m >>= 1) acc += __shfl_xor(acc, m, 64);
    if (lane == 0) red8[wid] = acc;
    __syncthreads();
    if (tid == 0) {
        double s = 0.0;
        #pragma unroll
        for (int w = 0; w < 8; ++w) s += red8[w];
        out[0] = (float)(0.5 * s);
    }
}

extern "C" void kernel_launch(void* const* d_in, const int* in_sizes, int n_in,
                              void* d_out, int out_size, void* d_ws, size_t ws_size,
                              hipStream_t stream) {
    const float* dgm   = (const float*)d_in[0];
    const float* dgm_x = (const float*)d_in[1];
    float* out = (float*)d_out;
    tofu_solver<<<1, 512, 0, stream>>>(dgm, dgm_x, out);
}